// Round 13
// baseline (1534.045 us; speedup 1.0000x reference)
//
#include <hip/hip_runtime.h>
#include <hip/hip_bf16.h>

typedef __hip_bfloat16 bf16;
typedef __attribute__((ext_vector_type(4))) float f32x4;
typedef __attribute__((ext_vector_type(8))) short s16x8;
typedef unsigned int u32;
typedef unsigned short u16;

#define B_ 16
#define T_ 4096
#define D_ 768
#define S_ 768
#define NS 16
#define NIT 9
#define NCHUNK 16
#define TCH 256
#define EPS 1e-8f
#define SCALE 0.036084391824351615f  /* 768^-0.5 */

__device__ __forceinline__ void gld16(const void* g, void* l) {
    __builtin_amdgcn_global_load_lds((const __attribute__((address_space(1))) u32*)g,
                                     (__attribute__((address_space(3))) u32*)l, 16, 0, 0);
}

__device__ __forceinline__ u16 bfbits(float x) {
    bf16 h = __float2bfloat16(x);
    return *reinterpret_cast<u16*>(&h);
}

// ---------------------------------------------------------------------------
__global__ void __launch_bounds__(256) cvt_all_kernel(
    const float* __restrict__ wq, const float* __restrict__ wk, const float* __restrict__ wv,
    const float* __restrict__ gwih, const float* __restrict__ gwhh,
    const float* __restrict__ w1, const float* __restrict__ w2,
    bf16* __restrict__ wq_b, bf16* __restrict__ wkv_b,
    bf16* __restrict__ gwih_b, bf16* __restrict__ gwhh_b,
    bf16* __restrict__ w1_b, bf16* __restrict__ w2_b)
{
    int i = blockIdx.x * 256 + threadIdx.x;
    const int NW = 589824, NG = 1769472, NM = 2359296;
    if (i < NW) { wq_b[i] = __float2bfloat16(wq[i]); return; }
    i -= NW;
    if (i < NW) { wkv_b[i] = __float2bfloat16(wk[i]); return; }
    i -= NW;
    if (i < NW) { wkv_b[NW + i] = __float2bfloat16(wv[i]); return; }
    i -= NW;
    if (i < NG) { gwih_b[i] = __float2bfloat16(gwih[i]); return; }
    i -= NG;
    if (i < NG) { gwhh_b[i] = __float2bfloat16(gwhh[i]); return; }
    i -= NG;
    if (i < NM) { w1_b[i] = __float2bfloat16(w1[i]); return; }
    i -= NM;
    w2_b[i] = __float2bfloat16(w2[i]);
}

// ---------------------------------------------------------------------------
// LayerNorm, 4 rows/block (one wave per row), float4 loads. grid = rows/4.
__global__ void __launch_bounds__(256) ln768_kernel(
    const float* __restrict__ x, const float* __restrict__ g,
    const float* __restrict__ bta, bf16* __restrict__ out)
{
    int wid = threadIdx.x >> 6, lane = threadIdx.x & 63;
    int row = blockIdx.x * 4 + wid;
    const float4* xr = (const float4*)(x + (size_t)row * 768);
    float4 v[3];
    float s = 0.f;
    #pragma unroll
    for (int i = 0; i < 3; ++i) {
        v[i] = xr[lane + i * 64];
        s += v[i].x + v[i].y + v[i].z + v[i].w;
    }
    #pragma unroll
    for (int off = 1; off < 64; off <<= 1) s += __shfl_xor(s, off);
    float mu = s * (1.f / 768.f);
    float q = 0.f;
    #pragma unroll
    for (int i = 0; i < 3; ++i) {
        float a = v[i].x - mu, b = v[i].y - mu, c = v[i].z - mu, d = v[i].w - mu;
        q += a * a + b * b + c * c + d * d;
    }
    #pragma unroll
    for (int off = 1; off < 64; off <<= 1) q += __shfl_xor(q, off);
    float rs = rsqrtf(q * (1.f / 768.f) + 1e-5f);
    ushort4* orow = (ushort4*)(out + (size_t)row * 768);
    const float4* gg = (const float4*)g;
    const float4* bb = (const float4*)bta;
    #pragma unroll
    for (int i = 0; i < 3; ++i) {
        float4 gv = gg[lane + i * 64], bv = bb[lane + i * 64];
        ushort4 o;
        o.x = bfbits((v[i].x - mu) * rs * gv.x + bv.x);
        o.y = bfbits((v[i].y - mu) * rs * gv.y + bv.y);
        o.z = bfbits((v[i].z - mu) * rs * gv.z + bv.z);
        o.w = bfbits((v[i].w - mu) * rs * gv.w + bv.w);
        orow[lane + i * 64] = o;
    }
}

// ---------------------------------------------------------------------------
// 256x128 NT GEMM for kv projection (round-6/10 proven).
__global__ void __launch_bounds__(512) gemm256_kernel(
    const bf16* __restrict__ A, const bf16* __restrict__ W,
    bf16* __restrict__ kout, bf16* __restrict__ vTout, float* __restrict__ vsum)
{
    __shared__ char smem[49152];
    __shared__ float vs_l[128];
    bf16* As = (bf16*)smem;
    bf16* Bs = (bf16*)(smem + 32768);
    int tid = threadIdx.x, lane = tid & 63, wid = tid >> 6;
    int bid = blockIdx.x;
    int xcd = bid & 7, idx = bid >> 3;
    int mt = xcd * 32 + idx / 12;
    int nt = idx % 12;
    int bm0 = mt * 256, bn0 = nt * 128;
    int wr = wid >> 1, wc = wid & 1;
    int g = lane >> 4, r15 = lane & 15;
    const f32x4 vzero = {0.f, 0.f, 0.f, 0.f};
    f32x4 acc[4][4];
    #pragma unroll
    for (int m = 0; m < 4; ++m)
        #pragma unroll
        for (int n = 0; n < 4; ++n) acc[m][n] = vzero;

    for (int kt = 0; kt < 768; kt += 64) {
        __syncthreads();
        #pragma unroll
        for (int i = 0; i < 4; ++i) {
            int s0 = i * 512 + wid * 64;
            int o = (s0 + lane) * 16;
            int r = o >> 7, cb = o & 127;
            int cbs = cb ^ ((r & 7) << 4);
            gld16(A + (size_t)(bm0 + r) * 768 + kt + (cbs >> 1), (char*)As + (size_t)s0 * 16);
        }
        #pragma unroll
        for (int i = 0; i < 2; ++i) {
            int s0 = i * 512 + wid * 64;
            int o = (s0 + lane) * 16;
            int r = o >> 7, cb = o & 127;
            int cbs = cb ^ ((r & 7) << 4);
            gld16(W + (size_t)(bn0 + r) * 768 + kt + (cbs >> 1), (char*)Bs + (size_t)s0 * 16);
        }
        asm volatile("s_waitcnt vmcnt(0)" ::: "memory");
        __syncthreads();
        #pragma unroll
        for (int kk2 = 0; kk2 < 2; ++kk2) {
            s16x8 af[4], bfr[4];
            #pragma unroll
            for (int m = 0; m < 4; ++m) {
                int r = wr * 64 + m * 16 + r15;
                int p = r * 128 + ((kk2 * 64 + g * 16) ^ ((r & 7) << 4));
                af[m] = *(const s16x8*)((const char*)As + p);
            }
            #pragma unroll
            for (int n = 0; n < 4; ++n) {
                int r = wc * 64 + n * 16 + r15;
                int p = r * 128 + ((kk2 * 64 + g * 16) ^ ((r & 7) << 4));
                bfr[n] = *(const s16x8*)((const char*)Bs + p);
            }
            #pragma unroll
            for (int m = 0; m < 4; ++m)
                #pragma unroll
                for (int n = 0; n < 4; ++n)
                    acc[m][n] = __builtin_amdgcn_mfma_f32_16x16x32_bf16(af[m], bfr[n], acc[m][n], 0, 0, 0);
        }
    }

    bool is_v = (bn0 >= 768);
    float* Ct = (float*)smem;                  // [64][132] f32
    int bq = bm0 >> 12;
    int tloc = bm0 & 4095;
    if (is_v && tid < 128) vs_l[tid] = 0.f;
    #pragma unroll
    for (int q = 0; q < 4; ++q) {
        __syncthreads();
        if (wr == q) {
            #pragma unroll
            for (int m = 0; m < 4; ++m)
                #pragma unroll
                for (int n = 0; n < 4; ++n)
                    #pragma unroll
                    for (int j = 0; j < 4; ++j)
                        Ct[(m * 16 + g * 4 + j) * 132 + wc * 64 + n * 16 + r15] = acc[m][n][j];
        }
        __syncthreads();
        if (!is_v) {
            int r = tid >> 3, cq = tid & 7;
            u16 tmp[16];
            #pragma unroll
            for (int i = 0; i < 4; ++i) {
                f32x4 vv = *(const f32x4*)&Ct[r * 132 + cq * 16 + i * 4];
                #pragma unroll
                for (int jj = 0; jj < 4; ++jj) tmp[i * 4 + jj] = bfbits(vv[jj]);
            }
            s16x8 o0, o1;
            #pragma unroll
            for (int i = 0; i < 8; ++i) { o0[i] = (short)tmp[i]; o1[i] = (short)tmp[8 + i]; }
            bf16* dst = kout + (size_t)(bm0 + q * 64 + r) * 768 + bn0 + cq * 16;
            *(s16x8*)dst = o0;
            *(s16x8*)(dst + 8) = o1;
        } else {
            int d = tid >> 2, tq = tid & 3;
            float ssum = 0.f;
            u16 tmp[16];
            #pragma unroll
            for (int i = 0; i < 16; ++i) {
                float f = Ct[(tq * 16 + i) * 132 + d];
                ssum += f;
                tmp[i] = bfbits(f);
            }
            s16x8 o0, o1;
            #pragma unroll
            for (int i = 0; i < 8; ++i) { o0[i] = (short)tmp[i]; o1[i] = (short)tmp[8 + i]; }
            bf16* dst = vTout + ((size_t)bq * 768 + (bn0 - 768) + d) * (size_t)T_
                        + tloc + q * 64 + tq * 16;
            *(s16x8*)dst = o0;
            *(s16x8*)(dst + 8) = o1;
            atomicAdd(&vs_l[d], ssum);
        }
    }
    if (is_v) {
        __syncthreads();
        if (tid < 128) atomicAdd(vsum + bq * 768 + (bn0 - 768) + tid, vs_l[tid]);
    }
}

// ---------------------------------------------------------------------------
__global__ void init_slots_kernel(const float* __restrict__ si,
                                  float* __restrict__ slots, bf16* __restrict__ slots_bf)
{
    int idx = blockIdx.x * 256 + threadIdx.x;
    float v = si[idx % (NS * S_)];
    slots[idx] = v;
    slots_bf[idx] = __float2bfloat16(v);
}

// ---------------------------------------------------------------------------
// Fused LN(16 rows) + NT GEMM with double-buffered staged W (round-6 proven).
__global__ void __launch_bounds__(256) ln_gemm_kernel(
    const float* __restrict__ xin, const float* __restrict__ gam, const float* __restrict__ bet,
    const bf16* __restrict__ W, const float* __restrict__ bias,
    bf16* __restrict__ out, int N, int relu)
{
    __shared__ bf16 As[16 * 768];
    __shared__ bf16 Ws[2][64 * 64];
    int tid = threadIdx.x;
    int bx = blockIdx.x, bn0 = blockIdx.y * 64;
    int row = tid >> 4, li = tid & 15;
    const float* xr = xin + (size_t)(bx * 16 + row) * 768;
    float vals[48];
    float s = 0.f;
    #pragma unroll
    for (int i = 0; i < 48; ++i) { vals[i] = xr[li + i * 16]; s += vals[i]; }
    #pragma unroll
    for (int m = 1; m < 16; m <<= 1) s += __shfl_xor(s, m);
    float mu = s * (1.f / 768.f);
    float q = 0.f;
    #pragma unroll
    for (int i = 0; i < 48; ++i) { float d = vals[i] - mu; q += d * d; }
    #pragma unroll
    for (int m = 1; m < 16; m <<= 1) q += __shfl_xor(q, m);
    float rs = rsqrtf(q * (1.f / 768.f) + 1e-5f);
    #pragma unroll
    for (int i = 0; i < 48; ++i) {
        int c = li + i * 16;
        float v = (vals[i] - mu) * rs * gam[c] + bet[c];
        *(u16*)((char*)As + row * 1536 + ((c * 2) ^ ((row & 7) << 4))) = bfbits(v);
    }
    int lane = tid & 63, wid = tid >> 6;
    int g = lane >> 4, s15 = lane & 15;
    auto stageW = [&](int kt, int buf) {
        #pragma unroll
        for (int i = 0; i < 2; ++i) {
            int s0 = i * 256 + wid * 64;
            int o = (s0 + lane) * 16;
            int r = o >> 7, cb = o & 127;
            int cbs = cb ^ ((r & 7) << 4);
            gld16(W + (size_t)(bn0 + r) * 768 + kt + (cbs >> 1),
                  (char*)Ws[buf] + (size_t)s0 * 16);
        }
    };
    stageW(0, 0);
    asm volatile("s_waitcnt vmcnt(0)" ::: "memory");
    __syncthreads();
    f32x4 acc = {0.f, 0.f, 0.f, 0.f};
    int rb = wid * 16 + s15;
    for (int t = 0; t < 12; ++t) {
        int cur = t & 1;
        if (t < 11) stageW((t + 1) * 64, cur ^ 1);
        #pragma unroll
        for (int kk2 = 0; kk2 < 2; ++kk2) {
            int kabs = t * 64 + kk2 * 32;
            s16x8 af = *(const s16x8*)((const char*)As + s15 * 1536 +
                                       ((kabs * 2 + g * 16) ^ ((s15 & 7) << 4)));
            s16x8 bf_ = *(const s16x8*)((const char*)Ws[cur] + rb * 128 +
                                        ((kk2 * 64 + g * 16) ^ ((rb & 7) << 4)));
            acc = __builtin_amdgcn_mfma_f32_16x16x32_bf16(af, bf_, acc, 0, 0, 0);
        }
        asm volatile("s_waitcnt vmcnt(0)" ::: "memory");
        __syncthreads();
    }
    int cn = bn0 + rb;
    float bv = bias ? bias[cn] : 0.f;
    #pragma unroll
    for (int j = 0; j < 4; ++j) {
        float val = acc[j] + bv;
        if (relu) val = fmaxf(val, 0.f);
        out[(size_t)(bx * 16 + g * 4 + j) * N + cn] = __float2bfloat16(val);
    }
}

// ---------------------------------------------------------------------------
// Fused GRU, BM=16: grid (16, 12) = 192 blocks, 52KB LDS (round-12 proven).
__global__ void __launch_bounds__(256) gru_fused16_kernel(
    const bf16* __restrict__ upd, const bf16* __restrict__ slotsA_bf,
    const bf16* __restrict__ Wih, const bf16* __restrict__ Whh,
    const float* __restrict__ bih, const float* __restrict__ bhh,
    const float* __restrict__ slotsA, float* __restrict__ slotsB)
{
    __shared__ char sm[53248];   // Au 2KB | Ah 2KB | 6 x W 8KB
    int tid = threadIdx.x, lane = tid & 63, wid = tid >> 6;
    int g = lane >> 4, r15 = lane & 15;
    int bm0 = blockIdx.x * 16, bn0 = blockIdx.y * 64;
    const f32x4 vz = {0.f, 0.f, 0.f, 0.f};
    f32x4 acc[6] = {vz, vz, vz, vz, vz, vz};

    for (int kt = 0; kt < 768; kt += 64) {
        __syncthreads();
        #pragma unroll
        for (int i = 0; i < 13; ++i) {
            int s0 = i * 256 + wid * 64;
            int seg = s0 + lane;
            const bf16* src;
            if (seg < 256) {
                int ls = seg & 127;
                int o = ls * 16;
                int r = o >> 7, cb = o & 127;
                int cbs = cb ^ ((r & 7) << 4);
                const bf16* base = (seg < 128) ? upd : slotsA_bf;
                src = base + (size_t)(bm0 + r) * 768 + kt + (cbs >> 1);
            } else {
                int ws = seg - 256;
                int p = ws >> 9, qq = ws & 511;
                int o = qq * 16;
                int r = o >> 7, cb = o & 127;
                int cbs = cb ^ ((r & 7) << 4);
                src = (p < 3)
                    ? Wih + (size_t)(p * 768 + bn0 + r) * 768 + kt + (cbs >> 1)
                    : Whh + (size_t)((p - 3) * 768 + bn0 + r) * 768 + kt + (cbs >> 1);
            }
            gld16(src, sm + (size_t)s0 * 16);
        }
        asm volatile("s_waitcnt vmcnt(0)" ::: "memory");
        __syncthreads();
        #pragma unroll
        for (int kk2 = 0; kk2 < 2; ++kk2) {
            int pa = r15 * 128 + ((kk2 * 64 + g * 16) ^ ((r15 & 7) << 4));
            s16x8 au = *(const s16x8*)(sm + pa);
            s16x8 ah = *(const s16x8*)(sm + 2048 + pa);
            int rb = wid * 16 + r15;
            int pb = rb * 128 + ((kk2 * 64 + g * 16) ^ ((rb & 7) << 4));
            #pragma unroll
            for (int p = 0; p < 6; ++p) {
                s16x8 wf = *(const s16x8*)(sm + 4096 + p * 8192 + pb);
                acc[p] = __builtin_amdgcn_mfma_f32_16x16x32_bf16(
                    (p < 3) ? au : ah, wf, acc[p], 0, 0, 0);
            }
        }
    }
    int cn = bn0 + wid * 16 + r15;
    float bir = bih[cn], biz = bih[768 + cn], bin_ = bih[1536 + cn];
    float bhr = bhh[cn], bhz = bhh[768 + cn], bhn = bhh[1536 + cn];
    #pragma unroll
    for (int j = 0; j < 4; ++j) {
        int m = bm0 + g * 4 + j;
        float ir = acc[0][j] + bir, iz = acc[1][j] + biz, inn = acc[2][j] + bin_;
        float hr = acc[3][j] + bhr, hz = acc[4][j] + bhz, hn = acc[5][j] + bhn;
        float rg = 1.f / (1.f + expf(-(ir + hr)));
        float z  = 1.f / (1.f + expf(-(iz + hz)));
        float nn = tanhf(inn + rg * hn);
        float h  = slotsA[(size_t)m * 768 + cn];
        slotsB[(size_t)m * 768 + cn] = (1.f - z) * nn + z * h;
    }
}

// ---------------------------------------------------------------------------
// Skinny NT GEMM body (round-6 proven) + mlp2 wrapper.
__device__ __forceinline__ void skinny_body(
    const bf16* A, const bf16* Bm, const float* bias, const float* Cin,
    float* Cf, bf16* Cb, int N, int K, int bm0, int bn0, int relu,
    bf16* As, bf16* Bs)
{
    int tid = threadIdx.x, lane = tid & 63, wid = tid >> 6;
    int g = lane >> 4, r15 = lane & 15;
    f32x4 acc = {0.f, 0.f, 0.f, 0.f};
    for (int kt = 0; kt < K; kt += 64) {
        __syncthreads();
        #pragma unroll
        for (int i = 0; i < 3; ++i) {
            int s0 = i * 256 + wid * 64;
            if (s0 < 640) {
                int o = (s0 + lane) * 16;
                if (o < 2048) {
                    int r = o >> 7, cb = o & 127;
                    int cbs = cb ^ ((r & 7) << 4);
                    gld16(A + (size_t)(bm0 + r) * K + kt + (cbs >> 1), (char*)As + (size_t)s0 * 16);
                } else {
                    int ob = o - 2048;
                    int r = ob >> 7, cb = ob & 127;
                    int cbs = cb ^ ((r & 7) << 4);
                    gld16(Bm + (size_t)(bn0 + r) * K + kt + (cbs >> 1),
                          (char*)Bs + (size_t)(s0 * 16 - 2048));
                }
            }
        }
        asm volatile("s_waitcnt vmcnt(0)" ::: "memory");
        __syncthreads();
        #pragma unroll
        for (int kk = 0; kk < 64; kk += 32) {
            int pa = r15 * 128 + ((kk * 2 + g * 16) ^ ((r15 & 7) << 4));
            s16x8 af = *(const s16x8*)((const char*)As + pa);
            int rb = wid * 16 + r15;
            int pb = rb * 128 + ((kk * 2 + g * 16) ^ ((rb & 7) << 4));
            s16x8 bfr = *(const s16x8*)((const char*)Bs + pb);
            acc = __builtin_amdgcn_mfma_f32_16x16x32_bf16(af, bfr, acc, 0, 0, 0);
        }
    }
    int cn = bn0 + wid * 16 + r15;
    float bv = bias ? bias[cn] : 0.f;
    #pragma unroll
    for (int j = 0; j < 4; ++j) {
        int cm = bm0 + g * 4 + j;
        size_t ci = (size_t)cm * N + cn;
        float val = acc[j] + bv;
        if (Cin) val += Cin[ci];
        if (relu) val = fmaxf(val, 0.f);
        if (Cf) Cf[ci] = val;
        if (Cb) Cb[ci] = __float2bfloat16(val);
    }
}

__global__ void __launch_bounds__(256) mlp2_kernel(
    const bf16* __restrict__ h1, const bf16* __restrict__ W2, const float* __restrict__ b2,
    const float* __restrict__ slotsB, float* __restrict__ slotsA, bf16* __restrict__ slotsA_bf)
{
    __shared__ bf16 As[16 * 64];
    __shared__ bf16 Bs[64 * 64];
    skinny_body(h1, W2, b2, slotsB, slotsA, slotsA_bf, 768, 3072,
                blockIdx.x * 16, blockIdx.y * 64, 0, As, Bs);
}

// ---------------------------------------------------------------------------
// Two-pass fused attention, half-slice (24KB) double-buffer, counted vmcnt,
// q in registers. LDS = 2x24KB + 8KB aL ~= 57KB -> 2 blocks/CU.
__global__ void __launch_bounds__(256) fused_attn_kernel(
    const bf16* __restrict__ q_bf, const bf16* __restrict__ k_bf, const bf16* __restrict__ vT,
    float* __restrict__ pU, float* __restrict__ prs, float* __restrict__ avis, int write_avis)
{
    __shared__ char smem[57344];
    bf16* ks0 = (bf16*)smem;                 // 24KB half-slice
    bf16* ks1 = (bf16*)(smem + 24576);       // 24KB half-slice
    char* aL  = smem + 49152;                // 8KB: [8 slices][16s][64B]
    __shared__ float rsw[2][16];
    int tid = threadIdx.x, lane = tid & 63, wid = tid >> 6;
    int b = blockIdx.x >> 4, chunk = blockIdx.x & 15;
    int t0 = chunk * TCH;
    int g = lane >> 4, s15 = lane & 15;
    const bf16* qb  = q_bf + (size_t)b * 16 * 768;
    const bf16* kb  = k_bf + (size_t)b * T_ * 768;
    const bf16* vtb = vT + (size_t)b * 768 * (size_t)T_;

    // k half-slice: [32 t-rows][384 K] rows of 768B, XOR-swizzled
    auto stage_kh = [&](int tb, int kh, bf16* dst) {
        #pragma unroll
        for (int i = 0; i < 6; ++i) {
            int s0 = i * 256 + wid * 64;
            int o = (s0 + lane) * 16;
            int r = o / 768, cb = o % 768;
            int cbs = cb ^ ((r & 7) << 4);
            gld16(kb + (size_t)(tb + r) * 768 + kh * 384 + (cbs >> 1),
                  (char*)dst + (size_t)s0 * 16);
        }
    };
    // vT half-slice: [384 d-rows][32 t] rows of 64B, XOR-swizzled
    auto stage_vh = [&](int tb, int dh, bf16* dst) {
        #pragma unroll
        for (int i = 0; i < 6; ++i) {
            int s0 = i * 256 + wid * 64;
            int o = (s0 + lane) * 16;
            int d = o >> 6, cb = o & 63;
            int cbs = cb ^ ((d & 3) << 4);
            gld16(vtb + (size_t)(dh * 384 + d) * T_ + tb + (cbs >> 1),
                  (char*)dst + (size_t)s0 * 16);
        }
    };

    // q fragments in registers (B-operand rows for waves 0-1)
    s16x8 qreg[24];
    #pragma unroll
    for (int i = 0; i < 24; ++i)
        qreg[i] = *(const s16x8*)(qb + (size_t)s15 * 768 + i * 32 + g * 8);

    const f32x4 vzero = {0.f, 0.f, 0.f, 0.f};
    float rs_acc = 0.f;

    // ---- pass 1: QK^T + softmax over slots ----
    {
        bf16* cur = ks0;
        bf16* nxt = ks1;
        stage_kh(t0, 0, cur);
        f32x4 dacc = vzero;
        for (int ts = 0; ts < 8; ++ts) {
            int tb = t0 + ts * 32;
            // half kh=0
            stage_kh(tb, 1, nxt);
            asm volatile("s_waitcnt vmcnt(6)" ::: "memory");
            __syncthreads();
            if (wid < 2) {
                dacc = vzero;
                #pragma unroll
                for (int ii = 0; ii < 12; ++ii) {
                    int rk = wid * 16 + s15;
                    int pk = rk * 768 + ((ii * 64 + g * 16) ^ ((rk & 7) << 4));
                    s16x8 kf = *(const s16x8*)((const char*)cur + pk);
                    dacc = __builtin_amdgcn_mfma_f32_16x16x32_bf16(kf, qreg[ii], dacc, 0, 0, 0);
                }
            }
            __syncthreads();
            { bf16* t = cur; cur = nxt; nxt = t; }
            // half kh=1
            if (ts < 7) {
                stage_kh(tb + 32, 0, nxt);
                asm volatile("s_waitcnt vmcnt(6)" ::: "memory");
            } else {
                asm volatile("s_waitcnt vmcnt(0)" ::: "memory");
            }
            __syncthreads();
            if (wid < 2) {
                #pragma unroll
                for (int ii = 0; ii < 12; ++ii) {
                    int rk = wid * 16 + s15;
                    int pk = rk * 768 + ((ii * 64 + g * 16) ^ ((rk & 7) << 4));
                    s16x8 kf = *(const s16x8*)((const char*)cur + pk);
                    dacc = __builtin_amdgcn_mfma_f32_16x16x32_bf16(kf, qreg[12 + ii], dacc, 0, 0, 0);
                }
                float d0 = dacc[0] * SCALE, d1 = dacc[1] * SCALE,
                      d2 = dacc[2] * SCALE, d3 = dacc[3] * SCALE;
                float m0 = d0, m1 = d1, m2 = d2, m3 = d3;
                #pragma unroll
                for (int off = 1; off < 16; off <<= 1) {
                    m0 = fmaxf(m0, __shfl_xor(m0, off));
                    m1 = fmaxf(m1, __shfl_xor(m1, off));
                    m2 = fmaxf(m2, __shfl_xor(m2, off));
                    m3 = fmaxf(m3, __shfl_xor(m3, off));
                }
                float e0 = expf(d0 - m0), e1 = expf(d1 - m1), e2 = expf(d2 - m2), e3 = expf(d3 - m3);
                float q0 = e0, q1 = e1, q2 = e2, q3 = e3;
                #pragma unroll
                for (int off = 1; off < 16; off <<= 1) {
                    q0 += __shfl_xor(q0, off);
                    q1 += __shfl_xor(q1, off);
                    q2 += __shfl_xor(q2, off);
                    q3 += __shfl_xor(q3, off);
                }
                float a0 = e0 / q0, a1 = e1 / q1, a2 = e2 / q2, a3 = e3 / q3;
                rs_acc += a0 + a1 + a2 + a3;
                int tl = wid * 16 + g * 4;
                ushort2 p0, p1;
                p0.x = bfbits(a0); p0.y = bfbits(a1);
                p1.x = bfbits(a2); p1.y = bfbits(a3);
                int sw = (s15 & 3) << 4;
                char* aS = aL + ts * 1024;
                *(ushort2*)(aS + s15 * 64 + ((tl * 2) ^ sw))       = p0;
                *(ushort2*)(aS + s15 * 64 + (((tl + 2) * 2) ^ sw)) = p1;
                if (write_avis) {
                    f32x4 wv = {a0, a1, a2, a3};
                    *(f32x4*)(avis + (size_t)(b * 16 + s15) * T_ + tb + tl) = wv;
                }
            }
            __syncthreads();
            { bf16* t = cur; cur = nxt; nxt = t; }
        }
    }

    // ---- pass 2: PV ----
    f32x4 uacc[12];
    #pragma unroll
    for (int i = 0; i < 12; ++i) uacc[i] = vzero;
    {
        bf16* cur = ks0;
        bf16* nxt = ks1;
        stage_vh(t0, 0, cur);
        for (int ts = 0; ts < 8; ++ts) {
            int tb = t0 + ts * 32;
            s16x8 afr;
            {
                int pa = ts * 1024 + s15 * 64 + ((g * 16) ^ ((s15 & 3) << 4));
                afr = *(const s16x8*)(aL + pa);
            }
            // half dh=0
            stage_vh(tb, 1, nxt);
            asm volatile("s_waitcnt vmcnt(6)" ::: "memory");
            __syncthreads();
            #pragma unroll
            for (int i = 0; i < 6; ++i) {
                int dl = (wid * 6 + i) * 16 + s15;
                int pv = dl * 64 + ((g * 16) ^ ((dl & 3) << 4));
                s16x8 vf = *(const s16x8*)((const char*)cur + pv);
                uacc[i] = __builtin_amdgcn_mfma_f32_16x16x32_bf16(vf, afr, uacc[i], 0, 0, 0);
            }
            __syncthreads();
            { bf16* t = cur; cur = nxt; nxt = t; }
            // half dh=1
            if (ts < 7) {
                stage_vh(tb + 32, 0, nxt);
                asm volatile("s_waitcnt vmcnt(6)" ::: "memory");
            } else {
                asm volatile("s_waitcnt vmcnt(0)" ::: "memory");
            }
            __syncthreads();
            #pragma unroll
            for (int i = 0; i < 6; ++i) {
                int dl = (wid * 6 + i) * 16 + s15;
                int pv = dl * 64 + ((g * 16) ^ ((dl & 3) << 4));
                s16x8 vf = *(const s16x8*)((const char*)cur + pv);
                uacc[6 + i] = __builtin_amdgcn_mfma_f32_16x16x32_bf16(vf, afr, uacc[6 + i], 0, 0, 0);
            }
            __syncthreads();
            { bf16* t = cur; cur = nxt; nxt = t; }
        }
    }

    // write partial U^T: [b][chunk][d][s]  (uacc[dh*6+i] -> d = dh*384 + (wid*6+i)*16 + ...)
    float* pUb = pU + (size_t)(b * 16 + chunk) * 768 * 16;
    #pragma unroll
    for (int dh = 0; dh < 2; ++dh)
        #pragma unroll
        for (int i = 0; i < 6; ++i) {
            int dbase = dh * 384 + (wid * 6 + i) * 16 + g * 4;
            #pragma unroll
            for (int j = 0; j < 4; ++j)
                pUb[(size_t)(dbase + j) * 16 + s15] = uacc[dh * 6 + i][j];
        }
    rs_acc += __shfl_xor(rs_acc, 16);
    rs_acc += __shfl_xor(rs_acc, 32);
    if (wid < 2 && lane < 16) rsw[wid][s15] = rs_acc;
    __syncthreads();
    if (tid < 16) prs[(b * 16 + chunk) * 16 + tid] = rsw[0][tid] + rsw[1][tid];
}

// reduce partials
__global__ void __launch_bounds__(256) attn_reduce_kernel(
    const float* __restrict__ pU, const float* __restrict__ prs,
    const float* __restrict__ vsum, bf16* __restrict__ upd)
{
    int idx = blockIdx.x * 256 + threadIdx.x;
    int d = idx % 768;
    int s = (idx / 768) & 15;
    int b = idx / (768 * 16);
    float su = 0.f;
    #pragma unroll
    for (int c = 0; c < 16; ++c) su += pU[((size_t)(b * 16 + c) * 768 + d) * 16 + s];
    float rs = 0.f;
    #pragma unroll
    for (int c = 0; c < 16; ++c) rs += prs[(b * 16 + c) * 16 + s];
    float val = (su + EPS * vsum[b * 768 + d]) / (rs + T_ * EPS);
    upd[idx] = __float2bfloat16(val);
}

// ---------------------------------------------------------------------------
__global__ void __launch_bounds__(256) cluster_kernel(
    const float* __restrict__ slots, float* __restrict__ out_slots,
    float* __restrict__ out_mask, float* __restrict__ cm_g)
{
    int b = blockIdx.x;
    __shared__ float s[16][768];
    __shared__ float inv[16];
    __shared__ float adj[16][16], tmp[16][16], cw[16][16];
    __shared__ int reset_s;
    const float* sb = slots + (size_t)b * 16 * 768;
    for (int i = threadIdx.x; i < 16 * 768; i += 256) s[i / 768][i % 768] = sb[i];
    __syncthreads();
    if (threadIdx.x < 16) {
        float q = 0.f;
        for (int d = 0; d < 768; ++d) q += s[threadIdx.x][d] * s[threadIdx.x][d];
        inv[threadIdx.x] = 1.f / fmaxf(sqrtf(q), 1e-12f);
    }
    __syncthreads();
    int n = threadIdx.x >> 4, m = threadIdx.x & 15;
    float dot = 0.f;
    for (int d = 0; d < 768; ++d) dot += s[n][d] * s[m][d];
    dot *= inv[n] * inv[m];
    adj[n][m] = ((1.f - dot) < 0.5f) ? 1.f : 0.f;
    __syncthreads();
    #pragma unroll
    for (int it = 0; it < 4; ++it) {
        float t = 0.f;
        #pragma unroll
        for (int j = 0; j < 16; ++j) t += adj[n][j] * adj[j][m];
        tmp[n][m] = fminf(t, 1.f);
        __syncthreads();
        adj[n][m] = tmp[n][m];
        __syncthreads();
    }
    if (threadIdx.x < 16) {
        int mm = threadIdx.x;
        float run = 0.f;
        for (int nn = 0; nn < 16; ++nn) {
            run += adj[nn][mm];
            tmp[nn][mm] = adj[nn][mm] * ((run <= 1.f) ? 1.f : 0.f);
        }
    }
    __syncthreads();
    if (threadIdx.x == 0) {
        int cnt2 = 0;
        for (int nn = 0; nn < 16; ++nn) {
            bool any = false;
            for (int j = 0; j < 16; ++j) any = any || (tmp[nn][j] > 0.f);
            cnt2 += any ? 1 : 0;
        }
        reset_s = (cnt2 < 3) ? 1 : 0;
    }
    __syncthreads();
    if (reset_s) tmp[n][m] = (n == m) ? 1.f : 0.f;
    __syncthreads();
    if (threadIdx.x < 16) {
        float rs = 0.f;
        for (int j = 0; j < 16; ++j) rs += tmp[threadIdx.x][j];
        rs = fmaxf(rs, 1.f);
        for (int j = 0; j < 16; ++j) cw[threadIdx.x][j] = tmp[threadIdx.x][j] / rs;
        bool any = false;
        for (int j = 0; j < 16; ++j) any = any || (tmp[threadIdx.x][j] > 0.f);
        out_mask[b * 16 + threadIdx.x] = any ? 1.f : 0.f;
    }
    cm_g[b * 256 + threadIdx.x] = tmp[n][m];
    __syncthreads();
    for (int i = threadIdx.x; i < 16 * 768; i += 256) {
        int nn = i / 768, d = i - nn * 768;
        float acc = 0.f;
        #pragma unroll
        for (int j = 0; j < 16; ++j) acc += cw[nn][j] * s[j][d];
        out_slots[(size_t)b * 16 * 768 + i] = acc;
    }
}

__global__ void __launch_bounds__(256) cattn_kernel(
    const float* __restrict__ av, const float* __restrict__ cm_g, float* __restrict__ out_attn)
{
    int b = blockIdx.y;
    int t = blockIdx.x * 256 + threadIdx.x;
    __shared__ float cm[16][16];
    cm[threadIdx.x >> 4][threadIdx.x & 15] = cm_g[b * 256 + threadIdx.x];
    __syncthreads();
    float avv[16];
    #pragma unroll
    for (int j = 0; j < 16; ++j) avv[j] = av[((size_t)b * 16 + j) * T_ + t];
    #pragma unroll
    for (int i = 0; i < 16; ++i) {
        float acc = 0.f;
        #pragma unroll
        for (int j = 0; j < 16; ++j) acc += cm[i][j] * avv[j];
        out_attn[((size_t)b * T_ + t) * 16 + i] = acc;
    }
}

// ---------------------------------------------------------------------------
extern "C" void kernel_launch(void* const* d_in, const int* in_sizes, int n_in,
                              void* d_out, int out_size, void* d_ws, size_t ws_size,
                              hipStream_t stream)
{
    const float* x    = (const float*)d_in[0];
    const float* si   = (const float*)d_in[3];
    const float* Wk   = (const float*)d_in[4];
    const float* Wv   = (const float*)d_in[5];
    const float* Wq   = (const float*)d_in[6];
    const float* gwih = (const float*)d_in[7];
    const float* gwhh = (const float*)d_in[8];
    const float* gbih = (const float*)d_in[9];
    const float* gbhh = (const float*)d_in[10];
    const float* w1   = (const float*)d_in[11];
    const float* b1   = (const float*)d_in[12];
    const float* w2   = (const float*)d_in[13];
    const float* b2   = (const float*)d_in[14];
    const float* ling = (const float*)d_in[15];
    const float* linb = (const float*)d_in[16];
    const float* lsg  = (const float*)d_in[17];
    const float* lsb  = (const float*)d_in[18];
    const float* lfg  = (const float*)d_in[19];
    const float* lfb  = (const float*)d_in[20];

    char* w = (char*)d_ws;
    size_t off = 0;
    auto alloc = [&](size_t bytes) { void* p = w + off; off += (bytes + 255) & ~(size_t)255; return p; };
    bf16* xn     = (bf16*)alloc((size_t)B_ * T_ * D_ * 2);
    bf16* k_bf   = (bf16*)alloc((size_t)B_ * T_ * S_ * 2);
    bf16* vT     = (bf16*)alloc((size_t)B_ * S_ * T_ * 2);
    float* avis  = (float*)alloc((size_t)B_ * NS * T_ * 4);
    float* pU    = (float*)alloc((size_t)B_ * NCHUNK * S_ * NS * 4);
    float* prs   = (float*)alloc((size_t)B_ * NCHUNK * NS * 4);
    float* vsum  = (float*)alloc((size_t)B_ * S_ * 4);
    float* slotsA = (float*)alloc((size_t)B_ * NS * S_ * 4);
    bf16* slotsA_bf = (bf16*)alloc((size_t)B_ * NS * S_ * 2);
    float* slotsB = (float*)alloc((size_t)B_ * NS * S_ * 4);
    bf16* q_bf   = (bf16*)alloc((size_t)B_ * NS * S_ * 2);
    bf16* upd_bf = (bf16*)alloc((size_t)B_ * NS * S_ * 2);
    bf16* h1_bf  = (bf16*)alloc((size_t)B_ * NS * 4 * S_ * 2);
    bf16* wq_bf  = (bf16*)alloc((size_t)S_ * S_ * 2);
    bf16* wkv_bf = (bf16*)alloc((size_t)1536 * D_ * 2);
    bf16* gwih_bf = (bf16*)alloc((size_t)3 * S_ * S_ * 2);
    bf16* gwhh_bf = (bf16*)alloc((size_t)3 * S_ * S_ * 2);
    bf16* w1_bf  = (bf16*)alloc((size_t)4 * S_ * S_ * 2);
    bf16* w2_bf  = (bf16*)alloc((size_t)S_ * 4 * S_ * 2);
    float* cm_g  = (float*)alloc((size_t)B_ * 256 * 4);

    float* out_slots = (float*)d_out;
    float* out_attn  = out_slots + (size_t)B_ * NS * S_;
    float* out_mask  = out_attn + (size_t)B_ * T_ * NS;

    cvt_all_kernel<<<39168, 256, 0, stream>>>(Wq, Wk, Wv, gwih, gwhh, w1, w2,
                                              wq_bf, wkv_bf, gwih_bf, gwhh_bf, w1_bf, w2_bf);

    ln768_kernel<<<B_ * T_ / 4, 256, 0, stream>>>(x, ling, linb, xn);

    (void)hipMemsetAsync(vsum, 0, (size_t)B_ * S_ * 4, stream);
    gemm256_kernel<<<3072, 512, 0, stream>>>(xn, wkv_bf, k_bf, vT, vsum);

    init_slots_kernel<<<(B_ * NS * S_) / 256, 256, 0, stream>>>(si, slotsA, slotsA_bf);

    for (int it = 0; it < NIT; ++it) {
        {
            dim3 g(16, 12);
            ln_gemm_kernel<<<g, 256, 0, stream>>>(slotsA, lsg, lsb, wq_bf, nullptr,
                                                  q_bf, 768, 0);
        }
        fused_attn_kernel<<<B_ * NCHUNK, 256, 0, stream>>>(q_bf, k_bf, vT, pU, prs, avis,
                                                           (it == NIT - 1) ? 1 : 0);
        attn_reduce_kernel<<<(B_ * NS * S_) / 256, 256, 0, stream>>>(pU, prs, vsum, upd_bf);
        {
            dim3 g(16, 12);
            gru_fused16_kernel<<<g, 256, 0, stream>>>(upd_bf, slotsA_bf, gwih_bf, gwhh_bf,
                                                      gbih, gbhh, slotsA, slotsB);
        }
        {
            dim3 g(16, 48);
            ln_gemm_kernel<<<g, 256, 0, stream>>>(slotsB, lfg, lfb, w1_bf, b1,
                                                  h1_bf, 3072, 1);
        }
        {
            dim3 g(16, 12);
            mlp2_kernel<<<g, 256, 0, stream>>>(h1_bf, w2_bf, b2, slotsB, slotsA, slotsA_bf);
        }
    }

    cluster_kernel<<<B_, 256, 0, stream>>>(slotsA, out_slots, out_mask, cm_g);
    {
        dim3 g(T_ / 256, B_);
        cattn_kernel<<<g, 256, 0, stream>>>(avis, cm_g, out_attn);
    }
}

// Round 14
// 1474.464 us; speedup vs baseline: 1.0404x; 1.0404x over previous
//
#include <hip/hip_runtime.h>
#include <hip/hip_bf16.h>

typedef __hip_bfloat16 bf16;
typedef __attribute__((ext_vector_type(4))) float f32x4;
typedef __attribute__((ext_vector_type(8))) short s16x8;
typedef unsigned int u32;
typedef unsigned short u16;

#define B_ 16
#define T_ 4096
#define D_ 768
#define S_ 768
#define NS 16
#define NIT 9
#define NCHUNK 16
#define TCH 256
#define EPS 1e-8f
#define SCALE 0.036084391824351615f  /* 768^-0.5 */

__device__ __forceinline__ void gld16(const void* g, void* l) {
    __builtin_amdgcn_global_load_lds((const __attribute__((address_space(1))) u32*)g,
                                     (__attribute__((address_space(3))) u32*)l, 16, 0, 0);
}

__device__ __forceinline__ u16 bfbits(float x) {
    bf16 h = __float2bfloat16(x);
    return *reinterpret_cast<u16*>(&h);
}

// ---------------------------------------------------------------------------
__global__ void __launch_bounds__(256) cvt_all_kernel(
    const float* __restrict__ wq, const float* __restrict__ wk, const float* __restrict__ wv,
    const float* __restrict__ gwih, const float* __restrict__ gwhh,
    const float* __restrict__ w1, const float* __restrict__ w2,
    bf16* __restrict__ wq_b, bf16* __restrict__ wkv_b,
    bf16* __restrict__ gwih_b, bf16* __restrict__ gwhh_b,
    bf16* __restrict__ w1_b, bf16* __restrict__ w2_b)
{
    int i = blockIdx.x * 256 + threadIdx.x;
    const int NW = 589824, NG = 1769472, NM = 2359296;
    if (i < NW) { wq_b[i] = __float2bfloat16(wq[i]); return; }
    i -= NW;
    if (i < NW) { wkv_b[i] = __float2bfloat16(wk[i]); return; }
    i -= NW;
    if (i < NW) { wkv_b[NW + i] = __float2bfloat16(wv[i]); return; }
    i -= NW;
    if (i < NG) { gwih_b[i] = __float2bfloat16(gwih[i]); return; }
    i -= NG;
    if (i < NG) { gwhh_b[i] = __float2bfloat16(gwhh[i]); return; }
    i -= NG;
    if (i < NM) { w1_b[i] = __float2bfloat16(w1[i]); return; }
    i -= NM;
    w2_b[i] = __float2bfloat16(w2[i]);
}

// ---------------------------------------------------------------------------
// LayerNorm, 4 rows/block (one wave per row), float4 loads. grid = rows/4.
__global__ void __launch_bounds__(256) ln768_kernel(
    const float* __restrict__ x, const float* __restrict__ g,
    const float* __restrict__ bta, bf16* __restrict__ out)
{
    int wid = threadIdx.x >> 6, lane = threadIdx.x & 63;
    int row = blockIdx.x * 4 + wid;
    const float4* xr = (const float4*)(x + (size_t)row * 768);
    float4 v[3];
    float s = 0.f;
    #pragma unroll
    for (int i = 0; i < 3; ++i) {
        v[i] = xr[lane + i * 64];
        s += v[i].x + v[i].y + v[i].z + v[i].w;
    }
    #pragma unroll
    for (int off = 1; off < 64; off <<= 1) s += __shfl_xor(s, off);
    float mu = s * (1.f / 768.f);
    float q = 0.f;
    #pragma unroll
    for (int i = 0; i < 3; ++i) {
        float a = v[i].x - mu, b = v[i].y - mu, c = v[i].z - mu, d = v[i].w - mu;
        q += a * a + b * b + c * c + d * d;
    }
    #pragma unroll
    for (int off = 1; off < 64; off <<= 1) q += __shfl_xor(q, off);
    float rs = rsqrtf(q * (1.f / 768.f) + 1e-5f);
    ushort4* orow = (ushort4*)(out + (size_t)row * 768);
    const float4* gg = (const float4*)g;
    const float4* bb = (const float4*)bta;
    #pragma unroll
    for (int i = 0; i < 3; ++i) {
        float4 gv = gg[lane + i * 64], bv = bb[lane + i * 64];
        ushort4 o;
        o.x = bfbits((v[i].x - mu) * rs * gv.x + bv.x);
        o.y = bfbits((v[i].y - mu) * rs * gv.y + bv.y);
        o.z = bfbits((v[i].z - mu) * rs * gv.z + bv.z);
        o.w = bfbits((v[i].w - mu) * rs * gv.w + bv.w);
        orow[lane + i * 64] = o;
    }
}

// ---------------------------------------------------------------------------
// 256x128 NT GEMM for kv projection. Epilogue stride 133 for v-path (2-way banks).
__global__ void __launch_bounds__(512) gemm256_kernel(
    const bf16* __restrict__ A, const bf16* __restrict__ W,
    bf16* __restrict__ kout, bf16* __restrict__ vTout, float* __restrict__ vsum)
{
    __shared__ char smem[49152];
    __shared__ float vs_l[128];
    bf16* As = (bf16*)smem;
    bf16* Bs = (bf16*)(smem + 32768);
    int tid = threadIdx.x, lane = tid & 63, wid = tid >> 6;
    int bid = blockIdx.x;
    int xcd = bid & 7, idx = bid >> 3;
    int mt = xcd * 32 + idx / 12;
    int nt = idx % 12;
    int bm0 = mt * 256, bn0 = nt * 128;
    int wr = wid >> 1, wc = wid & 1;
    int g = lane >> 4, r15 = lane & 15;
    const f32x4 vzero = {0.f, 0.f, 0.f, 0.f};
    f32x4 acc[4][4];
    #pragma unroll
    for (int m = 0; m < 4; ++m)
        #pragma unroll
        for (int n = 0; n < 4; ++n) acc[m][n] = vzero;

    for (int kt = 0; kt < 768; kt += 64) {
        __syncthreads();
        #pragma unroll
        for (int i = 0; i < 4; ++i) {
            int s0 = i * 512 + wid * 64;
            int o = (s0 + lane) * 16;
            int r = o >> 7, cb = o & 127;
            int cbs = cb ^ ((r & 7) << 4);
            gld16(A + (size_t)(bm0 + r) * 768 + kt + (cbs >> 1), (char*)As + (size_t)s0 * 16);
        }
        #pragma unroll
        for (int i = 0; i < 2; ++i) {
            int s0 = i * 512 + wid * 64;
            int o = (s0 + lane) * 16;
            int r = o >> 7, cb = o & 127;
            int cbs = cb ^ ((r & 7) << 4);
            gld16(W + (size_t)(bn0 + r) * 768 + kt + (cbs >> 1), (char*)Bs + (size_t)s0 * 16);
        }
        asm volatile("s_waitcnt vmcnt(0)" ::: "memory");
        __syncthreads();
        #pragma unroll
        for (int kk2 = 0; kk2 < 2; ++kk2) {
            s16x8 af[4], bfr[4];
            #pragma unroll
            for (int m = 0; m < 4; ++m) {
                int r = wr * 64 + m * 16 + r15;
                int p = r * 128 + ((kk2 * 64 + g * 16) ^ ((r & 7) << 4));
                af[m] = *(const s16x8*)((const char*)As + p);
            }
            #pragma unroll
            for (int n = 0; n < 4; ++n) {
                int r = wc * 64 + n * 16 + r15;
                int p = r * 128 + ((kk2 * 64 + g * 16) ^ ((r & 7) << 4));
                bfr[n] = *(const s16x8*)((const char*)Bs + p);
            }
            #pragma unroll
            for (int m = 0; m < 4; ++m)
                #pragma unroll
                for (int n = 0; n < 4; ++n)
                    acc[m][n] = __builtin_amdgcn_mfma_f32_16x16x32_bf16(af[m], bfr[n], acc[m][n], 0, 0, 0);
        }
    }

    bool is_v = (bn0 >= 768);
    float* Ct = (float*)smem;                  // [64][ldc] f32
    int ldc = is_v ? 133 : 132;                // 133 breaks the 4-way v-path conflict
    int bq = bm0 >> 12;
    int tloc = bm0 & 4095;
    if (is_v && tid < 128) vs_l[tid] = 0.f;
    #pragma unroll
    for (int q = 0; q < 4; ++q) {
        __syncthreads();
        if (wr == q) {
            #pragma unroll
            for (int m = 0; m < 4; ++m)
                #pragma unroll
                for (int n = 0; n < 4; ++n)
                    #pragma unroll
                    for (int j = 0; j < 4; ++j)
                        Ct[(m * 16 + g * 4 + j) * ldc + wc * 64 + n * 16 + r15] = acc[m][n][j];
        }
        __syncthreads();
        if (!is_v) {
            int r = tid >> 3, cq = tid & 7;
            u16 tmp[16];
            #pragma unroll
            for (int i = 0; i < 4; ++i) {
                f32x4 vv = *(const f32x4*)&Ct[r * 132 + cq * 16 + i * 4];
                #pragma unroll
                for (int jj = 0; jj < 4; ++jj) tmp[i * 4 + jj] = bfbits(vv[jj]);
            }
            s16x8 o0, o1;
            #pragma unroll
            for (int i = 0; i < 8; ++i) { o0[i] = (short)tmp[i]; o1[i] = (short)tmp[8 + i]; }
            bf16* dst = kout + (size_t)(bm0 + q * 64 + r) * 768 + bn0 + cq * 16;
            *(s16x8*)dst = o0;
            *(s16x8*)(dst + 8) = o1;
        } else {
            int d = tid >> 2, tq = tid & 3;
            float ssum = 0.f;
            u16 tmp[16];
            #pragma unroll
            for (int i = 0; i < 16; ++i) {
                float f = Ct[(tq * 16 + i) * 133 + d];
                ssum += f;
                tmp[i] = bfbits(f);
            }
            s16x8 o0, o1;
            #pragma unroll
            for (int i = 0; i < 8; ++i) { o0[i] = (short)tmp[i]; o1[i] = (short)tmp[8 + i]; }
            bf16* dst = vTout + ((size_t)bq * 768 + (bn0 - 768) + d) * (size_t)T_
                        + tloc + q * 64 + tq * 16;
            *(s16x8*)dst = o0;
            *(s16x8*)(dst + 8) = o1;
            atomicAdd(&vs_l[d], ssum);
        }
    }
    if (is_v) {
        __syncthreads();
        if (tid < 128) atomicAdd(vsum + bq * 768 + (bn0 - 768) + tid, vs_l[tid]);
    }
}

// ---------------------------------------------------------------------------
__global__ void init_slots_kernel(const float* __restrict__ si,
                                  float* __restrict__ slots, bf16* __restrict__ slots_bf)
{
    int idx = blockIdx.x * 256 + threadIdx.x;
    float v = si[idx % (NS * S_)];
    slots[idx] = v;
    slots_bf[idx] = __float2bfloat16(v);
}

// ---------------------------------------------------------------------------
// Fused LN(16 rows) + NT GEMM with double-buffered staged W (round-6 proven).
__global__ void __launch_bounds__(256) ln_gemm_kernel(
    const float* __restrict__ xin, const float* __restrict__ gam, const float* __restrict__ bet,
    const bf16* __restrict__ W, const float* __restrict__ bias,
    bf16* __restrict__ out, int N, int relu)
{
    __shared__ bf16 As[16 * 768];
    __shared__ bf16 Ws[2][64 * 64];
    int tid = threadIdx.x;
    int bx = blockIdx.x, bn0 = blockIdx.y * 64;
    int row = tid >> 4, li = tid & 15;
    const float* xr = xin + (size_t)(bx * 16 + row) * 768;
    float vals[48];
    float s = 0.f;
    #pragma unroll
    for (int i = 0; i < 48; ++i) { vals[i] = xr[li + i * 16]; s += vals[i]; }
    #pragma unroll
    for (int m = 1; m < 16; m <<= 1) s += __shfl_xor(s, m);
    float mu = s * (1.f / 768.f);
    float q = 0.f;
    #pragma unroll
    for (int i = 0; i < 48; ++i) { float d = vals[i] - mu; q += d * d; }
    #pragma unroll
    for (int m = 1; m < 16; m <<= 1) q += __shfl_xor(q, m);
    float rs = rsqrtf(q * (1.f / 768.f) + 1e-5f);
    #pragma unroll
    for (int i = 0; i < 48; ++i) {
        int c = li + i * 16;
        float v = (vals[i] - mu) * rs * gam[c] + bet[c];
        *(u16*)((char*)As + row * 1536 + ((c * 2) ^ ((row & 7) << 4))) = bfbits(v);
    }
    int lane = tid & 63, wid = tid >> 6;
    int g = lane >> 4, s15 = lane & 15;
    auto stageW = [&](int kt, int buf) {
        #pragma unroll
        for (int i = 0; i < 2; ++i) {
            int s0 = i * 256 + wid * 64;
            int o = (s0 + lane) * 16;
            int r = o >> 7, cb = o & 127;
            int cbs = cb ^ ((r & 7) << 4);
            gld16(W + (size_t)(bn0 + r) * 768 + kt + (cbs >> 1),
                  (char*)Ws[buf] + (size_t)s0 * 16);
        }
    };
    stageW(0, 0);
    asm volatile("s_waitcnt vmcnt(0)" ::: "memory");
    __syncthreads();
    f32x4 acc = {0.f, 0.f, 0.f, 0.f};
    int rb = wid * 16 + s15;
    for (int t = 0; t < 12; ++t) {
        int cur = t & 1;
        if (t < 11) stageW((t + 1) * 64, cur ^ 1);
        #pragma unroll
        for (int kk2 = 0; kk2 < 2; ++kk2) {
            int kabs = t * 64 + kk2 * 32;
            s16x8 af = *(const s16x8*)((const char*)As + s15 * 1536 +
                                       ((kabs * 2 + g * 16) ^ ((s15 & 7) << 4)));
            s16x8 bf_ = *(const s16x8*)((const char*)Ws[cur] + rb * 128 +
                                        ((kk2 * 64 + g * 16) ^ ((rb & 7) << 4)));
            acc = __builtin_amdgcn_mfma_f32_16x16x32_bf16(af, bf_, acc, 0, 0, 0);
        }
        asm volatile("s_waitcnt vmcnt(0)" ::: "memory");
        __syncthreads();
    }
    int cn = bn0 + rb;
    float bv = bias ? bias[cn] : 0.f;
    #pragma unroll
    for (int j = 0; j < 4; ++j) {
        float val = acc[j] + bv;
        if (relu) val = fmaxf(val, 0.f);
        out[(size_t)(bx * 16 + g * 4 + j) * N + cn] = __float2bfloat16(val);
    }
}

// ---------------------------------------------------------------------------
// Fused GRU, BM=16: grid (16, 12) = 192 blocks, 52KB LDS (round-12 proven).
__global__ void __launch_bounds__(256) gru_fused16_kernel(
    const bf16* __restrict__ upd, const bf16* __restrict__ slotsA_bf,
    const bf16* __restrict__ Wih, const bf16* __restrict__ Whh,
    const float* __restrict__ bih, const float* __restrict__ bhh,
    const float* __restrict__ slotsA, float* __restrict__ slotsB)
{
    __shared__ char sm[53248];   // Au 2KB | Ah 2KB | 6 x W 8KB
    int tid = threadIdx.x, lane = tid & 63, wid = tid >> 6;
    int g = lane >> 4, r15 = lane & 15;
    int bm0 = blockIdx.x * 16, bn0 = blockIdx.y * 64;
    const f32x4 vz = {0.f, 0.f, 0.f, 0.f};
    f32x4 acc[6] = {vz, vz, vz, vz, vz, vz};

    for (int kt = 0; kt < 768; kt += 64) {
        __syncthreads();
        #pragma unroll
        for (int i = 0; i < 13; ++i) {
            int s0 = i * 256 + wid * 64;
            int seg = s0 + lane;
            const bf16* src;
            if (seg < 256) {
                int ls = seg & 127;
                int o = ls * 16;
                int r = o >> 7, cb = o & 127;
                int cbs = cb ^ ((r & 7) << 4);
                const bf16* base = (seg < 128) ? upd : slotsA_bf;
                src = base + (size_t)(bm0 + r) * 768 + kt + (cbs >> 1);
            } else {
                int ws = seg - 256;
                int p = ws >> 9, qq = ws & 511;
                int o = qq * 16;
                int r = o >> 7, cb = o & 127;
                int cbs = cb ^ ((r & 7) << 4);
                src = (p < 3)
                    ? Wih + (size_t)(p * 768 + bn0 + r) * 768 + kt + (cbs >> 1)
                    : Whh + (size_t)((p - 3) * 768 + bn0 + r) * 768 + kt + (cbs >> 1);
            }
            gld16(src, sm + (size_t)s0 * 16);
        }
        asm volatile("s_waitcnt vmcnt(0)" ::: "memory");
        __syncthreads();
        #pragma unroll
        for (int kk2 = 0; kk2 < 2; ++kk2) {
            int pa = r15 * 128 + ((kk2 * 64 + g * 16) ^ ((r15 & 7) << 4));
            s16x8 au = *(const s16x8*)(sm + pa);
            s16x8 ah = *(const s16x8*)(sm + 2048 + pa);
            int rb = wid * 16 + r15;
            int pb = rb * 128 + ((kk2 * 64 + g * 16) ^ ((rb & 7) << 4));
            #pragma unroll
            for (int p = 0; p < 6; ++p) {
                s16x8 wf = *(const s16x8*)(sm + 4096 + p * 8192 + pb);
                acc[p] = __builtin_amdgcn_mfma_f32_16x16x32_bf16(
                    (p < 3) ? au : ah, wf, acc[p], 0, 0, 0);
            }
        }
    }
    int cn = bn0 + wid * 16 + r15;
    float bir = bih[cn], biz = bih[768 + cn], bin_ = bih[1536 + cn];
    float bhr = bhh[cn], bhz = bhh[768 + cn], bhn = bhh[1536 + cn];
    #pragma unroll
    for (int j = 0; j < 4; ++j) {
        int m = bm0 + g * 4 + j;
        float ir = acc[0][j] + bir, iz = acc[1][j] + biz, inn = acc[2][j] + bin_;
        float hr = acc[3][j] + bhr, hz = acc[4][j] + bhz, hn = acc[5][j] + bhn;
        float rg = 1.f / (1.f + expf(-(ir + hr)));
        float z  = 1.f / (1.f + expf(-(iz + hz)));
        float nn = tanhf(inn + rg * hn);
        float h  = slotsA[(size_t)m * 768 + cn];
        slotsB[(size_t)m * 768 + cn] = (1.f - z) * nn + z * h;
    }
}

// ---------------------------------------------------------------------------
// Skinny NT GEMM body (round-6 proven) + mlp2 wrapper.
__device__ __forceinline__ void skinny_body(
    const bf16* A, const bf16* Bm, const float* bias, const float* Cin,
    float* Cf, bf16* Cb, int N, int K, int bm0, int bn0, int relu,
    bf16* As, bf16* Bs)
{
    int tid = threadIdx.x, lane = tid & 63, wid = tid >> 6;
    int g = lane >> 4, r15 = lane & 15;
    f32x4 acc = {0.f, 0.f, 0.f, 0.f};
    for (int kt = 0; kt < K; kt += 64) {
        __syncthreads();
        #pragma unroll
        for (int i = 0; i < 3; ++i) {
            int s0 = i * 256 + wid * 64;
            if (s0 < 640) {
                int o = (s0 + lane) * 16;
                if (o < 2048) {
                    int r = o >> 7, cb = o & 127;
                    int cbs = cb ^ ((r & 7) << 4);
                    gld16(A + (size_t)(bm0 + r) * K + kt + (cbs >> 1), (char*)As + (size_t)s0 * 16);
                } else {
                    int ob = o - 2048;
                    int r = ob >> 7, cb = ob & 127;
                    int cbs = cb ^ ((r & 7) << 4);
                    gld16(Bm + (size_t)(bn0 + r) * K + kt + (cbs >> 1),
                          (char*)Bs + (size_t)(s0 * 16 - 2048));
                }
            }
        }
        asm volatile("s_waitcnt vmcnt(0)" ::: "memory");
        __syncthreads();
        #pragma unroll
        for (int kk = 0; kk < 64; kk += 32) {
            int pa = r15 * 128 + ((kk * 2 + g * 16) ^ ((r15 & 7) << 4));
            s16x8 af = *(const s16x8*)((const char*)As + pa);
            int rb = wid * 16 + r15;
            int pb = rb * 128 + ((kk * 2 + g * 16) ^ ((rb & 7) << 4));
            s16x8 bfr = *(const s16x8*)((const char*)Bs + pb);
            acc = __builtin_amdgcn_mfma_f32_16x16x32_bf16(af, bfr, acc, 0, 0, 0);
        }
    }
    int cn = bn0 + wid * 16 + r15;
    float bv = bias ? bias[cn] : 0.f;
    #pragma unroll
    for (int j = 0; j < 4; ++j) {
        int cm = bm0 + g * 4 + j;
        size_t ci = (size_t)cm * N + cn;
        float val = acc[j] + bv;
        if (Cin) val += Cin[ci];
        if (relu) val = fmaxf(val, 0.f);
        if (Cf) Cf[ci] = val;
        if (Cb) Cb[ci] = __float2bfloat16(val);
    }
}

__global__ void __launch_bounds__(256) mlp2_kernel(
    const bf16* __restrict__ h1, const bf16* __restrict__ W2, const float* __restrict__ b2,
    const float* __restrict__ slotsB, float* __restrict__ slotsA, bf16* __restrict__ slotsA_bf)
{
    __shared__ bf16 As[16 * 64];
    __shared__ bf16 Bs[64 * 64];
    skinny_body(h1, W2, b2, slotsB, slotsA, slotsA_bf, 768, 3072,
                blockIdx.x * 16, blockIdx.y * 64, 0, As, Bs);
}

// ---------------------------------------------------------------------------
// Two-pass fused attention, double-buffered slices (round-6/12 proven).
__global__ void __launch_bounds__(256) fused_attn_kernel(
    const bf16* __restrict__ q_bf, const bf16* __restrict__ k_bf, const bf16* __restrict__ vT,
    float* __restrict__ pU, float* __restrict__ prs, float* __restrict__ avis, int write_avis)
{
    __shared__ char smem[131072];
    bf16* ks0 = (bf16*)smem;
    bf16* ks1 = (bf16*)(smem + 49152);
    bf16* qs  = (bf16*)(smem + 98304);
    char* aL  = smem + 122880;
    __shared__ float rsw[2][16];
    int tid = threadIdx.x, lane = tid & 63, wid = tid >> 6;
    int b = blockIdx.x >> 4, chunk = blockIdx.x & 15;
    int t0 = chunk * TCH;
    int g = lane >> 4, s15 = lane & 15;
    const bf16* qb  = q_bf + (size_t)b * 16 * 768;
    const bf16* kb  = k_bf + (size_t)b * T_ * 768;
    const bf16* vtb = vT + (size_t)b * 768 * (size_t)T_;

    auto stage_k = [&](int tb, bf16* dst) {
        #pragma unroll
        for (int i = 0; i < 12; ++i) {
            int s0 = i * 256 + wid * 64;
            int o = (s0 + lane) * 16;
            int r = o / 1536, cb = o % 1536;
            int cbs = cb ^ ((r & 7) << 4);
            gld16(kb + (size_t)(tb + r) * 768 + (cbs >> 1), (char*)dst + (size_t)s0 * 16);
        }
    };
    auto stage_v = [&](int tb, bf16* dst) {
        #pragma unroll
        for (int i = 0; i < 12; ++i) {
            int s0 = i * 256 + wid * 64;
            int o = (s0 + lane) * 16;
            int d = o >> 6, cb = o & 63;
            int cbs = cb ^ ((d & 3) << 4);
            gld16(vtb + (size_t)d * T_ + tb + (cbs >> 1), (char*)dst + (size_t)s0 * 16);
        }
    };

    #pragma unroll
    for (int i = 0; i < 6; ++i) {
        int s0 = i * 256 + wid * 64;
        int o = (s0 + lane) * 16;
        int r = o / 1536, cb = o % 1536;
        int cbs = cb ^ ((r & 7) << 4);
        gld16(qb + (size_t)r * 768 + (cbs >> 1), (char*)qs + (size_t)s0 * 16);
    }
    stage_k(t0, ks0);
    asm volatile("s_waitcnt vmcnt(0)" ::: "memory");
    __syncthreads();

    const f32x4 vzero = {0.f, 0.f, 0.f, 0.f};
    float rs_acc = 0.f;

    // ---- pass 1: QK^T + softmax over slots ----
    for (int ts = 0; ts < 8; ++ts) {
        bf16* cur = (ts & 1) ? ks1 : ks0;
        bf16* nxt = (ts & 1) ? ks0 : ks1;
        if (ts < 7) stage_k(t0 + (ts + 1) * 32, nxt);
        if (wid < 2) {
            f32x4 dacc = vzero;
            #pragma unroll
            for (int kk = 0; kk < 768; kk += 32) {
                int rk = wid * 16 + s15;
                int pk = rk * 1536 + ((kk * 2 + g * 16) ^ ((rk & 7) << 4));
                s16x8 kf = *(const s16x8*)((const char*)cur + pk);
                int pq = s15 * 1536 + ((kk * 2 + g * 16) ^ ((s15 & 7) << 4));
                s16x8 qf = *(const s16x8*)((const char*)qs + pq);
                dacc = __builtin_amdgcn_mfma_f32_16x16x32_bf16(kf, qf, dacc, 0, 0, 0);
            }
            float d0 = dacc[0] * SCALE, d1 = dacc[1] * SCALE,
                  d2 = dacc[2] * SCALE, d3 = dacc[3] * SCALE;
            float m0 = d0, m1 = d1, m2 = d2, m3 = d3;
            #pragma unroll
            for (int off = 1; off < 16; off <<= 1) {
                m0 = fmaxf(m0, __shfl_xor(m0, off));
                m1 = fmaxf(m1, __shfl_xor(m1, off));
                m2 = fmaxf(m2, __shfl_xor(m2, off));
                m3 = fmaxf(m3, __shfl_xor(m3, off));
            }
            float e0 = expf(d0 - m0), e1 = expf(d1 - m1), e2 = expf(d2 - m2), e3 = expf(d3 - m3);
            float q0 = e0, q1 = e1, q2 = e2, q3 = e3;
            #pragma unroll
            for (int off = 1; off < 16; off <<= 1) {
                q0 += __shfl_xor(q0, off);
                q1 += __shfl_xor(q1, off);
                q2 += __shfl_xor(q2, off);
                q3 += __shfl_xor(q3, off);
            }
            float a0 = e0 / q0, a1 = e1 / q1, a2 = e2 / q2, a3 = e3 / q3;
            rs_acc += a0 + a1 + a2 + a3;
            int tl = wid * 16 + g * 4;
            ushort2 p0, p1;
            p0.x = bfbits(a0); p0.y = bfbits(a1);
            p1.x = bfbits(a2); p1.y = bfbits(a3);
            int sw = (s15 & 3) << 4;
            char* aS = aL + ts * 1024;
            *(ushort2*)(aS + s15 * 64 + ((tl * 2) ^ sw))       = p0;
            *(ushort2*)(aS + s15 * 64 + (((tl + 2) * 2) ^ sw)) = p1;
            if (write_avis) {
                f32x4 wv = {a0, a1, a2, a3};
                *(f32x4*)(avis + (size_t)(b * 16 + s15) * T_ + t0 + ts * 32 + tl) = wv;
            }
        }
        asm volatile("s_waitcnt vmcnt(0)" ::: "memory");
        __syncthreads();
    }

    // ---- pass 2: PV ----
    f32x4 uacc[12];
    #pragma unroll
    for (int i = 0; i < 12; ++i) uacc[i] = vzero;
    stage_v(t0, ks0);
    asm volatile("s_waitcnt vmcnt(0)" ::: "memory");
    __syncthreads();
    for (int ts = 0; ts < 8; ++ts) {
        bf16* cur = (ts & 1) ? ks1 : ks0;
        bf16* nxt = (ts & 1) ? ks0 : ks1;
        if (ts < 7) stage_v(t0 + (ts + 1) * 32, nxt);
        {
            int pa = ts * 1024 + s15 * 64 + ((g * 16) ^ ((s15 & 3) << 4));
            s16x8 afr = *(const s16x8*)(aL + pa);
            #pragma unroll
            for (int i = 0; i < 12; ++i) {
                int d = (wid * 12 + i) * 16 + s15;
                int pv = d * 64 + ((g * 16) ^ ((d & 3) << 4));
                s16x8 vf = *(const s16x8*)((const char*)cur + pv);
                uacc[i] = __builtin_amdgcn_mfma_f32_16x16x32_bf16(vf, afr, uacc[i], 0, 0, 0);
            }
        }
        asm volatile("s_waitcnt vmcnt(0)" ::: "memory");
        __syncthreads();
    }

    float* pUb = pU + (size_t)(b * 16 + chunk) * 768 * 16;
    #pragma unroll
    for (int i = 0; i < 12; ++i) {
        int dbase = (wid * 12 + i) * 16 + g * 4;
        #pragma unroll
        for (int j = 0; j < 4; ++j)
            pUb[(size_t)(dbase + j) * 16 + s15] = uacc[i][j];
    }
    rs_acc += __shfl_xor(rs_acc, 16);
    rs_acc += __shfl_xor(rs_acc, 32);
    if (wid < 2 && lane < 16) rsw[wid][s15] = rs_acc;
    __syncthreads();
    if (tid < 16) prs[(b * 16 + chunk) * 16 + tid] = rsw[0][tid] + rsw[1][tid];
}

// reduce partials
__global__ void __launch_bounds__(256) attn_reduce_kernel(
    const float* __restrict__ pU, const float* __restrict__ prs,
    const float* __restrict__ vsum, bf16* __restrict__ upd)
{
    int idx = blockIdx.x * 256 + threadIdx.x;
    int d = idx % 768;
    int s = (idx / 768) & 15;
    int b = idx / (768 * 16);
    float su = 0.f;
    #pragma unroll
    for (int c = 0; c < 16; ++c) su += pU[((size_t)(b * 16 + c) * 768 + d) * 16 + s];
    float rs = 0.f;
    #pragma unroll
    for (int c = 0; c < 16; ++c) rs += prs[(b * 16 + c) * 16 + s];
    float val = (su + EPS * vsum[b * 768 + d]) / (rs + T_ * EPS);
    upd[idx] = __float2bfloat16(val);
}

// ---------------------------------------------------------------------------
__global__ void __launch_bounds__(256) cluster_kernel(
    const float* __restrict__ slots, float* __restrict__ out_slots,
    float* __restrict__ out_mask, float* __restrict__ cm_g)
{
    int b = blockIdx.x;
    __shared__ float s[16][768];
    __shared__ float inv[16];
    __shared__ float adj[16][16], tmp[16][16], cw[16][16];
    __shared__ int reset_s;
    const float* sb = slots + (size_t)b * 16 * 768;
    for (int i = threadIdx.x; i < 16 * 768; i += 256) s[i / 768][i % 768] = sb[i];
    __syncthreads();
    if (threadIdx.x < 16) {
        float q = 0.f;
        for (int d = 0; d < 768; ++d) q += s[threadIdx.x][d] * s[threadIdx.x][d];
        inv[threadIdx.x] = 1.f / fmaxf(sqrtf(q), 1e-12f);
    }
    __syncthreads();
    int n = threadIdx.x >> 4, m = threadIdx.x & 15;
    float dot = 0.f;
    for (int d = 0; d < 768; ++d) dot += s[n][d] * s[m][d];
    dot *= inv[n] * inv[m];
    adj[n][m] = ((1.f - dot) < 0.5f) ? 1.f : 0.f;
    __syncthreads();
    #pragma unroll
    for (int it = 0; it < 4; ++it) {
        float t = 0.f;
        #pragma unroll
        for (int j = 0; j < 16; ++j) t += adj[n][j] * adj[j][m];
        tmp[n][m] = fminf(t, 1.f);
        __syncthreads();
        adj[n][m] = tmp[n][m];
        __syncthreads();
    }
    if (threadIdx.x < 16) {
        int mm = threadIdx.x;
        float run = 0.f;
        for (int nn = 0; nn < 16; ++nn) {
            run += adj[nn][mm];
            tmp[nn][mm] = adj[nn][mm] * ((run <= 1.f) ? 1.f : 0.f);
        }
    }
    __syncthreads();
    if (threadIdx.x == 0) {
        int cnt2 = 0;
        for (int nn = 0; nn < 16; ++nn) {
            bool any = false;
            for (int j = 0; j < 16; ++j) any = any || (tmp[nn][j] > 0.f);
            cnt2 += any ? 1 : 0;
        }
        reset_s = (cnt2 < 3) ? 1 : 0;
    }
    __syncthreads();
    if (reset_s) tmp[n][m] = (n == m) ? 1.f : 0.f;
    __syncthreads();
    if (threadIdx.x < 16) {
        float rs = 0.f;
        for (int j = 0; j < 16; ++j) rs += tmp[threadIdx.x][j];
        rs = fmaxf(rs, 1.f);
        for (int j = 0; j < 16; ++j) cw[threadIdx.x][j] = tmp[threadIdx.x][j] / rs;
        bool any = false;
        for (int j = 0; j < 16; ++j) any = any || (tmp[threadIdx.x][j] > 0.f);
        out_mask[b * 16 + threadIdx.x] = any ? 1.f : 0.f;
    }
    cm_g[b * 256 + threadIdx.x] = tmp[n][m];
    __syncthreads();
    for (int i = threadIdx.x; i < 16 * 768; i += 256) {
        int nn = i / 768, d = i - nn * 768;
        float acc = 0.f;
        #pragma unroll
        for (int j = 0; j < 16; ++j) acc += cw[nn][j] * s[j][d];
        out_slots[(size_t)b * 16 * 768 + i] = acc;
    }
}

__global__ void __launch_bounds__(256) cattn_kernel(
    const float* __restrict__ av, const float* __restrict__ cm_g, float* __restrict__ out_attn)
{
    int b = blockIdx.y;
    int t = blockIdx.x * 256 + threadIdx.x;
    __shared__ float cm[16][16];
    cm[threadIdx.x >> 4][threadIdx.x & 15] = cm_g[b * 256 + threadIdx.x];
    __syncthreads();
    float avv[16];
    #pragma unroll
    for (int j = 0; j < 16; ++j) avv[j] = av[((size_t)b * 16 + j) * T_ + t];
    #pragma unroll
    for (int i = 0; i < 16; ++i) {
        float acc = 0.f;
        #pragma unroll
        for (int j = 0; j < 16; ++j) acc += cm[i][j] * avv[j];
        out_attn[((size_t)b * T_ + t) * 16 + i] = acc;
    }
}

// ---------------------------------------------------------------------------
extern "C" void kernel_launch(void* const* d_in, const int* in_sizes, int n_in,
                              void* d_out, int out_size, void* d_ws, size_t ws_size,
                              hipStream_t stream)
{
    const float* x    = (const float*)d_in[0];
    const float* si   = (const float*)d_in[3];
    const float* Wk   = (const float*)d_in[4];
    const float* Wv   = (const float*)d_in[5];
    const float* Wq   = (const float*)d_in[6];
    const float* gwih = (const float*)d_in[7];
    const float* gwhh = (const float*)d_in[8];
    const float* gbih = (const float*)d_in[9];
    const float* gbhh = (const float*)d_in[10];
    const float* w1   = (const float*)d_in[11];
    const float* b1   = (const float*)d_in[12];
    const float* w2   = (const float*)d_in[13];
    const float* b2   = (const float*)d_in[14];
    const float* ling = (const float*)d_in[15];
    const float* linb = (const float*)d_in[16];
    const float* lsg  = (const float*)d_in[17];
    const float* lsb  = (const float*)d_in[18];
    const float* lfg  = (const float*)d_in[19];
    const float* lfb  = (const float*)d_in[20];

    char* w = (char*)d_ws;
    size_t off = 0;
    auto alloc = [&](size_t bytes) { void* p = w + off; off += (bytes + 255) & ~(size_t)255; return p; };
    bf16* xn     = (bf16*)alloc((size_t)B_ * T_ * D_ * 2);
    bf16* k_bf   = (bf16*)alloc((size_t)B_ * T_ * S_ * 2);
    bf16* vT     = (bf16*)alloc((size_t)B_ * S_ * T_ * 2);
    float* avis  = (float*)alloc((size_t)B_ * NS * T_ * 4);
    float* pU    = (float*)alloc((size_t)B_ * NCHUNK * S_ * NS * 4);
    float* prs   = (float*)alloc((size_t)B_ * NCHUNK * NS * 4);
    float* vsum  = (float*)alloc((size_t)B_ * S_ * 4);
    float* slotsA = (float*)alloc((size_t)B_ * NS * S_ * 4);
    bf16* slotsA_bf = (bf16*)alloc((size_t)B_ * NS * S_ * 2);
    float* slotsB = (float*)alloc((size_t)B_ * NS * S_ * 4);
    bf16* q_bf   = (bf16*)alloc((size_t)B_ * NS * S_ * 2);
    bf16* upd_bf = (bf16*)alloc((size_t)B_ * NS * S_ * 2);
    bf16* h1_bf  = (bf16*)alloc((size_t)B_ * NS * 4 * S_ * 2);
    bf16* wq_bf  = (bf16*)alloc((size_t)S_ * S_ * 2);
    bf16* wkv_bf = (bf16*)alloc((size_t)1536 * D_ * 2);
    bf16* gwih_bf = (bf16*)alloc((size_t)3 * S_ * S_ * 2);
    bf16* gwhh_bf = (bf16*)alloc((size_t)3 * S_ * S_ * 2);
    bf16* w1_bf  = (bf16*)alloc((size_t)4 * S_ * S_ * 2);
    bf16* w2_bf  = (bf16*)alloc((size_t)S_ * 4 * S_ * 2);
    float* cm_g  = (float*)alloc((size_t)B_ * 256 * 4);

    float* out_slots = (float*)d_out;
    float* out_attn  = out_slots + (size_t)B_ * NS * S_;
    float* out_mask  = out_attn + (size_t)B_ * T_ * NS;

    cvt_all_kernel<<<39168, 256, 0, stream>>>(Wq, Wk, Wv, gwih, gwhh, w1, w2,
                                              wq_bf, wkv_bf, gwih_bf, gwhh_bf, w1_bf, w2_bf);

    ln768_kernel<<<B_ * T_ / 4, 256, 0, stream>>>(x, ling, linb, xn);

    (void)hipMemsetAsync(vsum, 0, (size_t)B_ * S_ * 4, stream);
    gemm256_kernel<<<3072, 512, 0, stream>>>(xn, wkv_bf, k_bf, vT, vsum);

    init_slots_kernel<<<(B_ * NS * S_) / 256, 256, 0, stream>>>(si, slotsA, slotsA_bf);

    for (int it = 0; it < NIT; ++it) {
        {
            dim3 g(16, 12);
            ln_gemm_kernel<<<g, 256, 0, stream>>>(slotsA, lsg, lsb, wq_bf, nullptr,
                                                  q_bf, 768, 0);
        }
        fused_attn_kernel<<<B_ * NCHUNK, 256, 0, stream>>>(q_bf, k_bf, vT, pU, prs, avis,
                                                           (it == NIT - 1) ? 1 : 0);
        attn_reduce_kernel<<<(B_ * NS * S_) / 256, 256, 0, stream>>>(pU, prs, vsum, upd_bf);
        {
            dim3 g(16, 12);
            gru_fused16_kernel<<<g, 256, 0, stream>>>(upd_bf, slotsA_bf, gwih_bf, gwhh_bf,
                                                      gbih, gbhh, slotsA, slotsB);
        }
        {
            dim3 g(16, 48);
            ln_gemm_kernel<<<g, 256, 0, stream>>>(slotsB, lfg, lfb, w1_bf, b1,
                                                  h1_bf, 3072, 1);
        }
        {
            dim3 g(16, 12);
            mlp2_kernel<<<g, 256, 0, stream>>>(h1_bf, w2_bf, b2, slotsB, slotsA, slotsA_bf);
        }
    }

    cluster_kernel<<<B_, 256, 0, stream>>>(slotsA, out_slots, out_mask, cm_g);
    {
        dim3 g(T_ / 256, B_);
        cattn_kernel<<<g, 256, 0, stream>>>(avis, cm_g, out_attn);
    }
}